// Round 7
// baseline (338.061 us; speedup 1.0000x reference)
//
#include <hip/hip_runtime.h>
#include <hip/hip_cooperative_groups.h>
#include <stdint.h>

namespace cg = cooperative_groups;

#define S_GRID 7
#define N_CH 30
#define MAXB 8192          // max compacted boxes (actual data: 6272)
#define NTILE 32           // j-tiles (covers MAXB columns at 256/tile)
#define NCHUNK 32          // i-chunks
#define GRID_BLOCKS (NTILE*NCHUNK)   // 1024 = 4 blocks/CU on 256 CUs

// ---- ws layout (bytes) ----
// 0      : float acc[4] {xy+wh, obj, nobj, class}
// 16     : int finalCtr
// 20     : int hdr       (nb = 2*ncoord)
// 64     : float pcls[128]   (per-prep-block class partials)
// 576    : float pnobj[128]  (per-prep-block noobj partials)
// 4096   : float4 BP[MAXB]   (131072) -> 135168
// 135168 : float4 BT[MAXB]   (131072) -> 266240
// 266240 : float  ConfP[MAXB] (32768) -> 299008
// 299008 : float  AreaP[MAXB] (32768) -> 331776
// 331776 : u64 pkeys[NCHUNK][MAXB]  (2 MiB)

__global__ __launch_bounds__(256, 4)
void k_fused(const float* __restrict__ P, const float* __restrict__ T, int ncell,
             float4* __restrict__ BP, float4* __restrict__ BT,
             float* __restrict__ ConfP, float* __restrict__ AreaP,
             float* __restrict__ pcls, float* __restrict__ pnobj,
             float* __restrict__ acc, int* __restrict__ finalCtr, int* __restrict__ hdr,
             unsigned long long* __restrict__ pkeys,
             float* __restrict__ out, float inv_batch, int nblkPrep) {
    cg::grid_group grid = cg::this_grid();
    int b = blockIdx.x, tid = threadIdx.x;
    int lane = tid & 63, wid = tid >> 6;

    // ---------------- Phase A: prep (blocks 0..nblkPrep-1) ----------------
    if (b < nblkPrep) {
        int cell = b * 256 + tid;
        const float* p = P + (size_t)cell * N_CH;
        const float* t = T + (size_t)cell * N_CH;
        bool obj = (cell < ncell) && (t[4] == 1.0f);

        if (b == 0) {
            if (tid < 4)  acc[tid] = 0.0f;
            if (tid == 4) *finalCtr = 0;
        }

        // exclusive prefix of obj count over cells [0, b*256), recomputed redundantly
        int pre = 0;
        int limit = b * 256;
        for (int c = tid; c < limit; c += 256)
            pre += (T[(size_t)c * N_CH + 4] == 1.0f) ? 1 : 0;
        #pragma unroll
        for (int o = 32; o; o >>= 1) pre += __shfl_down(pre, o);

        unsigned long long bm = __ballot(obj);

        float cls = 0.f, nob = 0.f;
        if (cell < ncell) {
            if (obj) {
                #pragma unroll
                for (int k = 10; k < 30; k++) { float d = p[k] - t[k]; cls += d * d; }
            } else {
                float d0 = p[4] - t[4], d1 = p[9] - t[9];
                nob = d0 * d0 + d1 * d1;
            }
        }
        #pragma unroll
        for (int o = 32; o; o >>= 1) { cls += __shfl_down(cls, o); nob += __shfl_down(nob, o); }

        __shared__ int   shPre[4], shCnt[4], shOfs[4];
        __shared__ float shC[4], shN[4];
        if (lane == 0) {
            shPre[wid] = pre; shCnt[wid] = __popcll(bm);
            shC[wid] = cls;   shN[wid] = nob;
        }
        __syncthreads();
        if (tid == 0) {
            int base = shPre[0] + shPre[1] + shPre[2] + shPre[3];
            int s = 0;
            #pragma unroll
            for (int w = 0; w < 4; w++) { shOfs[w] = base + s; s += shCnt[w]; }
            pcls[b]  = shC[0] + shC[1] + shC[2] + shC[3];
            pnobj[b] = shN[0] + shN[1] + shN[2] + shN[3];
            if (b == nblkPrep - 1) hdr[0] = 2 * (base + s);   // nb
        }
        __syncthreads();

        if (obj) {
            int rank = shOfs[wid] + __popcll(bm & ((1ull << lane) - 1ull));
            #pragma unroll
            for (int bb = 0; bb < 2; ++bb) {
                int m = 2 * rank + bb;
                if (m < MAXB) {
                    int o5 = bb * 5;
                    float cx = p[o5 + 0] / (float)S_GRID, cy = p[o5 + 1] / (float)S_GRID;
                    float w = p[o5 + 2], h = p[o5 + 3];
                    float4 bp = make_float4(cx - 0.5f * w, cy - 0.5f * h,
                                            cx + 0.5f * w, cy + 0.5f * h);
                    BP[m] = bp;
                    AreaP[m] = (bp.z - bp.x) * (bp.w - bp.y);
                    ConfP[m] = p[4 + o5];
                    cx = t[o5 + 0] / (float)S_GRID; cy = t[o5 + 1] / (float)S_GRID;
                    w = t[o5 + 2]; h = t[o5 + 3];
                    BT[m] = make_float4(cx - 0.5f * w, cy - 0.5f * h,
                                        cx + 0.5f * w, cy + 0.5f * h);
                }
            }
        }
    }

    grid.sync();

    // ---------------- Phase B: match (all blocks; jt = b>>5, c = b&31) ----------------
    int nb = hdr[0]; if (nb > MAXB) nb = MAXB;
    int chunkLen = (nb + NCHUNK - 1) / NCHUNK;
    {
        int jt = b >> 5, c = b & (NCHUNK - 1);
        int j = jt * 256 + tid;
        int i0 = c * chunkLen;
        int i1 = min(nb, i0 + chunkLen);
        if (j < nb && i0 < i1) {
            float4 tb = BT[j];
            float a2 = (tb.z - tb.x) * (tb.w - tb.y);
            // divide-free argmax: iou_i > iou_best  <=>  inter_i*bestD > bestN*u_i
            float bestN = -1.f, bestD = 1.f;
            int bidx = 0;
            #pragma unroll 2
            for (int i = i0; i < i1; ++i) {
                float4 pb = BP[i];             // wave-uniform -> scalar loads
                float a1 = AreaP[i];
                float lx = fmaxf(pb.x, tb.x), ly = fmaxf(pb.y, tb.y);
                float rx = fminf(pb.z, tb.z), ry = fminf(pb.w, tb.w);
                float wx = fmaxf(rx - lx, 0.f), wy = fmaxf(ry - ly, 0.f);
                float inter = wx * wy;
                float u = (a1 + a2) - inter;
                if (__builtin_expect(inter * bestD > bestN * u, 0)) {
                    bestN = inter; bestD = u; bidx = i;
                }
            }
            float best = bestN / bestD;        // one precise divide per (j,chunk)
            pkeys[(size_t)c * MAXB + j] =
                ((unsigned long long)__float_as_uint(best) << 32) |
                (unsigned long long)(0xFFFFFFFFu - (unsigned)bidx);
        }
    }

    grid.sync();

    // ---------------- Phase C: gather + final (blocks 0..NTILE-1) ----------------
    if (b < NTILE) {
        int j = b * 256 + tid;
        float sxywh = 0.f, sobj = 0.f;
        if (j < nb) {
            unsigned long long key = 0;
            #pragma unroll 4
            for (int c = 0; c < NCHUNK; ++c) {
                if (c * chunkLen >= nb) break;
                unsigned long long k2 = pkeys[(size_t)c * MAXB + j];
                if (k2 > key) key = k2;      // bigger iou wins; ties -> smaller idx
            }
            float iou = __uint_as_float((unsigned)(key >> 32));
            unsigned idx = 0xFFFFFFFFu - (unsigned)(key & 0xFFFFFFFFull);
            float4 bp = BP[idx], bt = BT[idx];
            float cp = ConfP[idx];
            float dx = bp.x - bt.x, dy = bp.y - bt.y;
            float dw = sqrtf(bp.z) - sqrtf(bt.z);
            float dh = sqrtf(bp.w) - sqrtf(bt.w);
            sxywh = dx * dx + dy * dy + dw * dw + dh * dh;
            float dob = cp - iou;
            sobj = dob * dob;
        }
        float exC = 0.f, exN = 0.f;
        if (b == 0 && tid < nblkPrep) { exC = pcls[tid]; exN = pnobj[tid]; }

        #pragma unroll
        for (int o = 32; o; o >>= 1) {
            sxywh += __shfl_down(sxywh, o); sobj += __shfl_down(sobj, o);
            exC   += __shfl_down(exC, o);   exN  += __shfl_down(exN, o);
        }
        if ((tid & 63) == 0) {
            if (sxywh != 0.f) atomicAdd(&acc[0], sxywh);
            if (sobj != 0.f)  atomicAdd(&acc[1], sobj);
            if (exN != 0.f)   atomicAdd(&acc[2], exN);
            if (exC != 0.f)   atomicAdd(&acc[3], exC);
        }
        __syncthreads();                 // drains wave-leader atomics
        if (tid == 0) {
            int old = __hip_atomic_fetch_add(finalCtr, 1, __ATOMIC_ACQ_REL,
                                             __HIP_MEMORY_SCOPE_AGENT);
            if (old == NTILE - 1) {      // last block: all adds visible
                float a0 = __hip_atomic_load(&acc[0], __ATOMIC_RELAXED, __HIP_MEMORY_SCOPE_AGENT);
                float a1 = __hip_atomic_load(&acc[1], __ATOMIC_RELAXED, __HIP_MEMORY_SCOPE_AGENT);
                float a2 = __hip_atomic_load(&acc[2], __ATOMIC_RELAXED, __HIP_MEMORY_SCOPE_AGENT);
                float a3 = __hip_atomic_load(&acc[3], __ATOMIC_RELAXED, __HIP_MEMORY_SCOPE_AGENT);
                out[0] = (5.0f * a0 + 0.5f * a2 + a1 + a3) * inv_batch;
            }
        }
    }
}

extern "C" void kernel_launch(void* const* d_in, const int* in_sizes, int n_in,
                              void* d_out, int out_size, void* d_ws, size_t ws_size,
                              hipStream_t stream) {
    const float* P = (const float*)d_in[0];
    const float* T = (const float*)d_in[1];
    int ncell = in_sizes[0] / N_CH;                 // 25088
    int batch = ncell / (S_GRID * S_GRID);          // 512

    char* ws = (char*)d_ws;
    float* acc      = (float*)ws;
    int*   finalCtr = (int*)(ws + 16);
    int*   hdr      = (int*)(ws + 20);
    float* pcls     = (float*)(ws + 64);
    float* pnobj    = (float*)(ws + 576);
    float4* BP    = (float4*)(ws + 4096);
    float4* BT    = (float4*)(ws + 135168);
    float*  ConfP = (float*)(ws + 266240);
    float*  AreaP = (float*)(ws + 299008);
    unsigned long long* pkeys = (unsigned long long*)(ws + 331776);

    int nblkPrep = (ncell + 255) / 256;             // 98 (<=128 for pcls/pnobj)
    float inv_batch = 1.0f / (float)batch;
    float* outp = (float*)d_out;

    void* args[] = {
        (void*)&P, (void*)&T, (void*)&ncell,
        (void*)&BP, (void*)&BT, (void*)&ConfP, (void*)&AreaP,
        (void*)&pcls, (void*)&pnobj,
        (void*)&acc, (void*)&finalCtr, (void*)&hdr,
        (void*)&pkeys, (void*)&outp, (void*)&inv_batch, (void*)&nblkPrep
    };
    hipLaunchCooperativeKernel((const void*)k_fused,
                               dim3(GRID_BLOCKS), dim3(256),
                               args, 0, stream);
}

// Round 8
// 62.088 us; speedup vs baseline: 5.4449x; 5.4449x over previous
//
#include <hip/hip_runtime.h>
#include <stdint.h>

#define S_GRID 7
#define N_CH 30
#define MAXB 8192          // max compacted boxes (actual data: 6272)
#define NTILE 32           // gather j-tiles (256 cols each)
#define NCHUNK 8           // i-chunks
#define JG 8               // j-columns per wave in k_match

// ---- ws layout (bytes) ----
// 0      : float acc[4] {xy+wh, obj, nobj, class}
// 16     : int finalCtr
// 20     : int hdr       (nb = 2*ncoord)
// 64     : float pcls[128]   (per-prep-block class partials)
// 576    : float pnobj[128]  (per-prep-block noobj partials)
// 4096   : float4 BP[MAXB]   (131072) -> 135168
// 135168 : float4 BT[MAXB]   (131072) -> 266240
// 266240 : float  ConfP[MAXB] (32768) -> 299008
// 299008 : float  AreaP[MAXB] (32768) -> 331776
// 331776 : u64 pkeys[NCHUNK][MAXB]  (512 KiB)

// ONE pass over P,T, no pre-zeroed state needed (unchanged from R6):
__global__ void k_prep(const float* __restrict__ P, const float* __restrict__ T, int ncell,
                       float4* __restrict__ BP, float4* __restrict__ BT,
                       float* __restrict__ ConfP, float* __restrict__ AreaP,
                       float* __restrict__ pcls, float* __restrict__ pnobj,
                       float* __restrict__ acc, int* __restrict__ finalCtr,
                       int* __restrict__ hdr) {
    int b = blockIdx.x, tid = threadIdx.x;
    int lane = tid & 63, wid = tid >> 6;
    int cell = b * 256 + tid;
    const float* p = P + (size_t)cell * N_CH;
    const float* t = T + (size_t)cell * N_CH;
    bool obj = (cell < ncell) && (t[4] == 1.0f);

    if (b == 0) {
        if (tid < 4)  acc[tid] = 0.0f;
        if (tid == 4) *finalCtr = 0;
    }

    // exclusive prefix of obj count over cells [0, b*256), recomputed redundantly
    int pre = 0;
    int limit = b * 256;
    for (int c = tid; c < limit; c += 256)
        pre += (T[(size_t)c * N_CH + 4] == 1.0f) ? 1 : 0;
    #pragma unroll
    for (int o = 32; o; o >>= 1) pre += __shfl_down(pre, o);

    unsigned long long bm = __ballot(obj);

    float cls = 0.f, nob = 0.f;
    if (cell < ncell) {
        if (obj) {
            #pragma unroll
            for (int k = 10; k < 30; k++) { float d = p[k] - t[k]; cls += d * d; }
        } else {
            float d0 = p[4] - t[4], d1 = p[9] - t[9];
            nob = d0 * d0 + d1 * d1;
        }
    }
    #pragma unroll
    for (int o = 32; o; o >>= 1) { cls += __shfl_down(cls, o); nob += __shfl_down(nob, o); }

    __shared__ int   shPre[4], shCnt[4], shOfs[4];
    __shared__ float shC[4], shN[4];
    if (lane == 0) {
        shPre[wid] = pre; shCnt[wid] = __popcll(bm);
        shC[wid] = cls;   shN[wid] = nob;
    }
    __syncthreads();
    if (tid == 0) {
        int base = shPre[0] + shPre[1] + shPre[2] + shPre[3];
        int s = 0;
        #pragma unroll
        for (int w = 0; w < 4; w++) { shOfs[w] = base + s; s += shCnt[w]; }
        pcls[b]  = shC[0] + shC[1] + shC[2] + shC[3];
        pnobj[b] = shN[0] + shN[1] + shN[2] + shN[3];
        if (b == gridDim.x - 1) hdr[0] = 2 * (base + s);   // nb
    }
    __syncthreads();

    if (obj) {
        int rank = shOfs[wid] + __popcll(bm & ((1ull << lane) - 1ull));
        #pragma unroll
        for (int bb = 0; bb < 2; ++bb) {
            int m = 2 * rank + bb;
            if (m < MAXB) {
                int o5 = bb * 5;
                float cx = p[o5 + 0] / (float)S_GRID, cy = p[o5 + 1] / (float)S_GRID;
                float w = p[o5 + 2], h = p[o5 + 3];
                float4 bp = make_float4(cx - 0.5f * w, cy - 0.5f * h, cx + 0.5f * w, cy + 0.5f * h);
                BP[m] = bp;
                AreaP[m] = (bp.z - bp.x) * (bp.w - bp.y);
                ConfP[m] = p[4 + o5];
                cx = t[o5 + 0] / (float)S_GRID; cy = t[o5 + 1] / (float)S_GRID;
                w = t[o5 + 2]; h = t[o5 + 3];
                BT[m] = make_float4(cx - 0.5f * w, cy - 0.5f * h, cx + 0.5f * w, cy + 0.5f * h);
            }
        }
    }
}

// wave-centric match: lane l streams box i (coalesced VECTOR loads -> no scalar-unit
// bottleneck); each wave holds JG target boxes wave-uniform (8 s_loads total).
// Per 64-step: 8x64 IoUs in VALU, divide-free running argmax; shuffle-reduce at end.
__global__ void k_match(const float4* __restrict__ BP, const float4* __restrict__ BT,
                        const float* __restrict__ AreaP,
                        const int* __restrict__ hdr,
                        unsigned long long* __restrict__ pkeys) {
    int nb = hdr[0]; if (nb > MAXB) nb = MAXB;
    int lane = threadIdx.x & 63, wid = threadIdx.x >> 6;
    int wgrp = blockIdx.x * 4 + wid;         // wave-group: JG consecutive j's
    int j0 = wgrp * JG;
    int c = blockIdx.y;
    int chunkLen = (nb + NCHUNK - 1) / NCHUNK;
    int i0 = c * chunkLen;
    int i1 = min(nb, i0 + chunkLen);
    if (j0 >= nb || i0 >= i1) return;

    float4 tb[JG]; float ta[JG];
    #pragma unroll
    for (int jj = 0; jj < JG; ++jj) {
        float4 t = BT[min(j0 + jj, nb - 1)]; // wave-uniform -> scalar regs
        tb[jj] = t;
        ta[jj] = (t.z - t.x) * (t.w - t.y);
    }
    float bestN[JG], bestD[JG]; int bidx[JG];
    #pragma unroll
    for (int jj = 0; jj < JG; ++jj) { bestN[jj] = -1.f; bestD[jj] = 1.f; bidx[jj] = 0; }

    for (int ib = i0; ib < i1; ib += 64) {
        int i = ib + lane;
        bool v = i < i1;
        int ic = v ? i : i1 - 1;             // clamped load, guarded update
        float4 pb = BP[ic];
        float a1 = AreaP[ic];
        #pragma unroll
        for (int jj = 0; jj < JG; ++jj) {
            float lx = fmaxf(pb.x, tb[jj].x), ly = fmaxf(pb.y, tb[jj].y);
            float rx = fminf(pb.z, tb[jj].z), ry = fminf(pb.w, tb[jj].w);
            float wx = fmaxf(rx - lx, 0.f), wy = fmaxf(ry - ly, 0.f);
            float inter = wx * wy;
            float u = (a1 + ta[jj]) - inter;
            // iou_i > iou_best  <=>  inter*bestD > bestN*u  (all >=0 once valid, u>0);
            // first valid i always beats the (-1,1) init.
            bool win = v && (inter * bestD[jj] > bestN[jj] * u);
            bestN[jj] = win ? inter : bestN[jj];
            bestD[jj] = win ? u : bestD[jj];
            bidx[jj]  = win ? i : bidx[jj];
        }
    }

    #pragma unroll
    for (int jj = 0; jj < JG; ++jj) {
        unsigned long long key = 0;          // lanes with no valid i contribute 0 (< any valid key)
        if (bestN[jj] >= 0.f) {
            float r;                         // approx rcp: rel err ~1e-7; threshold is 0.89 abs
            asm("v_rcp_f32 %0, %1" : "=v"(r) : "v"(bestD[jj]));
            float best = bestN[jj] * r;
            key = ((unsigned long long)__float_as_uint(best) << 32) |
                  (unsigned long long)(0xFFFFFFFFu - (unsigned)bidx[jj]);
        }
        #pragma unroll
        for (int o = 32; o; o >>= 1) {       // max-reduce to lane 0 (ties -> smaller idx)
            unsigned lo = (unsigned)key, hi = (unsigned)(key >> 32);
            unsigned lo2 = (unsigned)__shfl_down((int)lo, o);
            unsigned hi2 = (unsigned)__shfl_down((int)hi, o);
            unsigned long long other = ((unsigned long long)hi2 << 32) | lo2;
            if (other > key) key = other;
        }
        if (lane == 0 && j0 + jj < nb)
            pkeys[(size_t)c * MAXB + (j0 + jj)] = key;
    }
}

// gather + partial-array summation + final combine (unchanged from R6, NCHUNK=8)
__global__ void k_gather(const float4* __restrict__ BP, const float4* __restrict__ BT,
                         const float* __restrict__ ConfP,
                         const int* __restrict__ hdr,
                         const unsigned long long* __restrict__ pkeys,
                         const float* __restrict__ pcls, const float* __restrict__ pnobj, int nblk,
                         float* __restrict__ acc, int* __restrict__ finalCtr,
                         float* __restrict__ out, float inv_batch) {
    int nb = hdr[0]; if (nb > MAXB) nb = MAXB;
    int tid = threadIdx.x;
    int j = blockIdx.x * 256 + tid;
    float sxywh = 0.f, sobj = 0.f;
    if (j < nb) {
        int chunkLen = (nb + NCHUNK - 1) / NCHUNK;
        unsigned long long key = 0;
        #pragma unroll
        for (int c = 0; c < NCHUNK; ++c) {
            if (c * chunkLen >= nb) break;   // empty chunks were never written
            unsigned long long k2 = pkeys[(size_t)c * MAXB + j];
            if (k2 > key) key = k2;          // bigger iou wins; ties -> smaller idx
        }
        float iou = __uint_as_float((unsigned)(key >> 32));
        unsigned idx = 0xFFFFFFFFu - (unsigned)(key & 0xFFFFFFFFull);
        float4 bp = BP[idx], bt = BT[idx];
        float cp = ConfP[idx];
        float dx = bp.x - bt.x, dy = bp.y - bt.y;
        float dw = sqrtf(bp.z) - sqrtf(bt.z);
        float dh = sqrtf(bp.w) - sqrtf(bt.w);
        sxywh = dx * dx + dy * dy + dw * dw + dh * dh;
        float dob = cp - iou;
        sobj = dob * dob;
    }
    float exC = 0.f, exN = 0.f;
    if (blockIdx.x == 0 && tid < nblk) { exC = pcls[tid]; exN = pnobj[tid]; }

    #pragma unroll
    for (int o = 32; o; o >>= 1) {
        sxywh += __shfl_down(sxywh, o); sobj += __shfl_down(sobj, o);
        exC   += __shfl_down(exC, o);   exN  += __shfl_down(exN, o);
    }
    if ((tid & 63) == 0) {
        if (sxywh != 0.f) atomicAdd(&acc[0], sxywh);
        if (sobj != 0.f)  atomicAdd(&acc[1], sobj);
        if (exN != 0.f)   atomicAdd(&acc[2], exN);
        if (exC != 0.f)   atomicAdd(&acc[3], exC);
    }
    __syncthreads();                         // drains wave-leader atomics
    if (tid == 0) {
        int old = __hip_atomic_fetch_add(finalCtr, 1, __ATOMIC_ACQ_REL, __HIP_MEMORY_SCOPE_AGENT);
        if (old == NTILE - 1) {              // last block: all adds visible
            float a0 = __hip_atomic_load(&acc[0], __ATOMIC_RELAXED, __HIP_MEMORY_SCOPE_AGENT);
            float a1 = __hip_atomic_load(&acc[1], __ATOMIC_RELAXED, __HIP_MEMORY_SCOPE_AGENT);
            float a2 = __hip_atomic_load(&acc[2], __ATOMIC_RELAXED, __HIP_MEMORY_SCOPE_AGENT);
            float a3 = __hip_atomic_load(&acc[3], __ATOMIC_RELAXED, __HIP_MEMORY_SCOPE_AGENT);
            out[0] = (5.0f * a0 + 0.5f * a2 + a1 + a3) * inv_batch;
        }
    }
}

extern "C" void kernel_launch(void* const* d_in, const int* in_sizes, int n_in,
                              void* d_out, int out_size, void* d_ws, size_t ws_size,
                              hipStream_t stream) {
    const float* P = (const float*)d_in[0];
    const float* T = (const float*)d_in[1];
    int ncell = in_sizes[0] / N_CH;                 // 25088
    int batch = ncell / (S_GRID * S_GRID);          // 512

    char* ws = (char*)d_ws;
    float* acc      = (float*)ws;
    int*   finalCtr = (int*)(ws + 16);
    int*   hdr      = (int*)(ws + 20);
    float* pcls     = (float*)(ws + 64);
    float* pnobj    = (float*)(ws + 576);
    float4* BP    = (float4*)(ws + 4096);
    float4* BT    = (float4*)(ws + 135168);
    float*  ConfP = (float*)(ws + 266240);
    float*  AreaP = (float*)(ws + 299008);
    unsigned long long* pkeys = (unsigned long long*)(ws + 331776);

    int nblk = (ncell + 255) / 256;                 // 98 (<=128 for pcls/pnobj)
    k_prep  <<<nblk, 256, 0, stream>>>(P, T, ncell, BP, BT, ConfP, AreaP,
                                       pcls, pnobj, acc, finalCtr, hdr);
    // x: wave-groups of JG columns (4 waves/block), sized for MAXB; idle groups exit
    dim3 g3(MAXB / (4 * JG), NCHUNK);               // (256, 8)
    k_match <<<g3, 256, 0, stream>>>(BP, BT, AreaP, hdr, pkeys);
    k_gather<<<NTILE, 256, 0, stream>>>(BP, BT, ConfP, hdr, pkeys, pcls, pnobj, nblk,
                                        acc, finalCtr, (float*)d_out, 1.0f / (float)batch);
}